// Round 4
// baseline (303.070 us; speedup 1.0000x reference)
//
#include <hip/hip_runtime.h>
#include <stdint.h>

#define B_  4
#define S_  2048
#define D_  1024
#define H_  16
#define DK_ 64
#define M_  (B_ * S_)

typedef __attribute__((ext_vector_type(8))) short bf16x8;
typedef __attribute__((ext_vector_type(4))) float f32x4;

// Q pre-scale: 1/sqrt(64) * log2(e)  (scores land in exp2 domain)
#define QSCALE 0.1803368801111204f

__device__ __forceinline__ uint16_t f2bf(float f) {
    uint32_t u = __builtin_bit_cast(uint32_t, f);
    u = (u + 0x7FFFu + ((u >> 16) & 1u)) >> 16;   // round-to-nearest-even
    return (uint16_t)u;
}

// pack two f32 -> bf16x2 (lo in low half), round-half-up, 3 VALU ops
__device__ __forceinline__ uint32_t pk2bf(float hi, float lo) {
    uint32_t a = __builtin_bit_cast(uint32_t, hi) + 0x8000u;
    uint32_t b = __builtin_bit_cast(uint32_t, lo) + 0x8000u;
    return __builtin_amdgcn_perm(a, b, 0x07060302u);
}

// ---------------------------------------------------------------------------
// fp32 -> bf16 elementwise convert, 8 elems/thread
// ---------------------------------------------------------------------------
__global__ __launch_bounds__(256) void cvt_bf16_kernel(const float* __restrict__ in,
                                                       uint16_t* __restrict__ out, int n) {
    int i = (blockIdx.x * 256 + threadIdx.x) * 8;
    if (i >= n) return;
    float4 a = *(const float4*)&in[i];
    float4 b = *(const float4*)&in[i + 4];
    uint16_t o[8] = {f2bf(a.x), f2bf(a.y), f2bf(a.z), f2bf(a.w),
                     f2bf(b.x), f2bf(b.y), f2bf(b.z), f2bf(b.w)};
    *(uint4*)&out[i] = *(const uint4*)o;
}

// ---------------------------------------------------------------------------
// transpose + convert: in [R][C] fp32 -> out [C][R] bf16, per-matrix batch on z
// ---------------------------------------------------------------------------
__global__ __launch_bounds__(256) void transpose_cvt_kernel(
    const float* __restrict__ in, uint16_t* __restrict__ out, int R, int C) {
    __shared__ __align__(16) uint16_t tile[64][72];
    const int mat = blockIdx.z;
    const float* inm = in + (size_t)mat * R * C;
    uint16_t* outm = out + (size_t)mat * R * C;
    const int r0 = blockIdx.x * 64, c0 = blockIdx.y * 64;
    const int t = threadIdx.x;
    const int lr = t >> 2, lc = (t & 3) * 16;
    uint16_t tmp[16];
    #pragma unroll
    for (int j = 0; j < 16; j += 4) {
        float4 v = *(const float4*)&inm[(size_t)(r0 + lr) * C + c0 + lc + j];
        tmp[j] = f2bf(v.x); tmp[j + 1] = f2bf(v.y); tmp[j + 2] = f2bf(v.z); tmp[j + 3] = f2bf(v.w);
    }
    *(uint4*)&tile[lr][lc]     = ((const uint4*)tmp)[0];
    *(uint4*)&tile[lr][lc + 8] = ((const uint4*)tmp)[1];
    __syncthreads();
    const int oc = t >> 2, orr = (t & 3) * 16;
    uint16_t ot[16];
    #pragma unroll
    for (int j = 0; j < 16; ++j) ot[j] = tile[orr + j][oc];
    *(uint4*)&outm[(size_t)(c0 + oc) * R + r0 + orr]     = ((const uint4*)ot)[0];
    *(uint4*)&outm[(size_t)(c0 + oc) * R + r0 + orr + 8] = ((const uint4*)ot)[1];
}

// ---------------------------------------------------------------------------
// QKV projection, MFMA. C[128 x 128] per block; 4 waves in 2x2, 64x64/wave.
// Wt pre-transposed [n_global][k], n_global = sel*1024 + h*64 + dk.
// Q pre-scaled by QSCALE (exp2 domain). V written TRANSPOSED [bh][dk][s]
// with vectorized uint2 stores (4 consecutive s per lane).
// ---------------------------------------------------------------------------
__global__ __launch_bounds__(256) void qkv_mfma_kernel(
    const uint16_t* __restrict__ xb, const uint16_t* __restrict__ Wt,
    const float* __restrict__ bq, const float* __restrict__ bk, const float* __restrict__ bv,
    uint16_t* __restrict__ Q, uint16_t* __restrict__ K, uint16_t* __restrict__ V)
{
    __shared__ __align__(16) uint16_t As[128][72];
    __shared__ __align__(16) uint16_t Bs[128][72];
    const int tid = threadIdx.x;
    const int nb = blockIdx.x;                  // 0..23
    const int sel = nb >> 3, npair = nb & 7;
    const int m0 = blockIdx.y * 128;
    const int lane = tid & 63, w = tid >> 6;
    const int wr = w >> 1, wc = w & 1;
    const int ll = lane & 15, quad = lane >> 4;

    const uint16_t* Bg = Wt + (size_t)nb * 128 * 1024;
    const float* bias = (sel == 0) ? bq : (sel == 1) ? bk : bv;

    const int ar = tid >> 1, ac = (tid & 1) * 32;

    f32x4 acc[4][4];
    const f32x4 zz = {0.f, 0.f, 0.f, 0.f};
    #pragma unroll
    for (int i = 0; i < 4; ++i)
        #pragma unroll
        for (int j = 0; j < 4; ++j) acc[i][j] = zz;

    for (int k0 = 0; k0 < 1024; k0 += 64) {
        __syncthreads();
        const uint16_t* ag = &xb[(size_t)(m0 + ar) * 1024 + k0 + ac];
        uint4 a0 = *(const uint4*)(ag);
        uint4 a1 = *(const uint4*)(ag + 8);
        uint4 a2 = *(const uint4*)(ag + 16);
        uint4 a3 = *(const uint4*)(ag + 24);
        const uint16_t* bg = &Bg[(size_t)ar * 1024 + k0 + ac];
        uint4 b0 = *(const uint4*)(bg);
        uint4 b1 = *(const uint4*)(bg + 8);
        uint4 b2 = *(const uint4*)(bg + 16);
        uint4 b3 = *(const uint4*)(bg + 24);
        *(uint4*)&As[ar][ac]      = a0;
        *(uint4*)&As[ar][ac + 8]  = a1;
        *(uint4*)&As[ar][ac + 16] = a2;
        *(uint4*)&As[ar][ac + 24] = a3;
        *(uint4*)&Bs[ar][ac]      = b0;
        *(uint4*)&Bs[ar][ac + 8]  = b1;
        *(uint4*)&Bs[ar][ac + 16] = b2;
        *(uint4*)&Bs[ar][ac + 24] = b3;
        __syncthreads();
        #pragma unroll
        for (int ks = 0; ks < 2; ++ks) {
            bf16x8 af[4], bfv[4];
            #pragma unroll
            for (int mt = 0; mt < 4; ++mt)
                af[mt] = *(const bf16x8*)&As[wr * 64 + mt * 16 + ll][ks * 32 + quad * 8];
            #pragma unroll
            for (int nt = 0; nt < 4; ++nt)
                bfv[nt] = *(const bf16x8*)&Bs[wc * 64 + nt * 16 + ll][ks * 32 + quad * 8];
            #pragma unroll
            for (int mt = 0; mt < 4; ++mt)
                #pragma unroll
                for (int nt = 0; nt < 4; ++nt)
                    acc[mt][nt] = __builtin_amdgcn_mfma_f32_16x16x32_bf16(af[mt], bfv[nt], acc[mt][nt], 0, 0, 0);
        }
    }

    if (sel == 2) {
        // V transposed: V[(b*16+hh)*64 + dk][s], 4 consecutive s per store
        #pragma unroll
        for (int nt = 0; nt < 4; ++nt) {
            const int nl = wc * 64 + nt * 16 + ll;
            const int hh = npair * 2 + (nl >> 6);
            const int dk = nl & 63;
            const float bval = bias[npair * 128 + nl];
            #pragma unroll
            for (int mt = 0; mt < 4; ++mt) {
                int m = m0 + wr * 64 + mt * 16 + quad * 4;
                int b = m >> 11, s = m & 2047;
                uint2 pv;
                pv.x = pk2bf(acc[mt][nt][1] + bval, acc[mt][nt][0] + bval);
                pv.y = pk2bf(acc[mt][nt][3] + bval, acc[mt][nt][2] + bval);
                *(uint2*)&V[((size_t)(b * 16 + hh) * 64 + dk) * 2048 + s] = pv;
            }
        }
    } else {
        uint16_t* Out = (sel == 0) ? Q : K;
        const float qs = (sel == 0) ? QSCALE : 1.0f;
        #pragma unroll
        for (int nt = 0; nt < 4; ++nt) {
            const int nl = wc * 64 + nt * 16 + ll;
            const int hh = npair * 2 + (nl >> 6);
            const int dk = nl & 63;
            const float bval = bias[npair * 128 + nl];
            #pragma unroll
            for (int mt = 0; mt < 4; ++mt) {
                #pragma unroll
                for (int r = 0; r < 4; ++r) {
                    int m = m0 + wr * 64 + mt * 16 + quad * 4 + r;
                    int b = m >> 11, s = m & 2047;
                    float v = (acc[mt][nt][r] + bval) * qs;
                    Out[((size_t)(b * 16 + hh) * 2048 + s) * 64 + dk] = f2bf(v);
                }
            }
        }
    }
}

// ---------------------------------------------------------------------------
// Flash attention, MFMA, S^T = K·Q^T. 64-row q-tiles; block pairs tiles
// (31-p, p) for uniform 33 kt-tiles/block. Q fragments direct from global
// (no Qs LDS). V pre-transposed [bh][dk][s] -> pure vector staging.
// exp2-domain softmax (scale folded into Q), no running max.
// ---------------------------------------------------------------------------
__global__ __launch_bounds__(256) void attn_mfma_kernel(
    const uint16_t* __restrict__ Q, const uint16_t* __restrict__ K,
    const uint16_t* __restrict__ Vg, uint16_t* __restrict__ CAT)
{
    __shared__ __align__(16) uint16_t Ks[64][72];
    __shared__ __align__(16) uint16_t Vt[64][72];
    __shared__ __align__(16) uint16_t Ps[64][72];
    __shared__ __align__(16) float rbuf[64];

    const int tid = threadIdx.x;
    const int lane = tid & 63, w = tid >> 6;
    const int ll = lane & 15, quad = lane >> 4;
    const int p = blockIdx.x;          // 0..15
    const int bh = blockIdx.y;
    const int b = bh >> 4, h = bh & 15;

    const uint16_t* Qbh = Q + (size_t)bh * S_ * 64;
    const uint16_t* Kbh = K + (size_t)bh * S_ * 64;
    const uint16_t* Vbh = Vg + (size_t)bh * 64 * S_;   // [dk][s]
    uint16_t* Cbh = CAT + (size_t)b * 2048 * 1024 + h * 64;

    const int sr = tid >> 2, sc = (tid & 3) * 16;      // staging coords

    #pragma unroll 1
    for (int phase = 0; phase < 2; ++phase) {
        const int qtb = (phase == 0) ? (31 - p) : p;
        const int q0 = qtb * 64;
        const int qw = q0 + w * 16;     // this wave's q rows [qw, qw+16)
        const int qg = qw + ll;         // this lane's q row (n-index of S^T)

        bf16x8 qf[2];
        #pragma unroll
        for (int ks = 0; ks < 2; ++ks)
            qf[ks] = *(const bf16x8*)&Qbh[(size_t)(qw + ll) * 64 + ks * 32 + quad * 8];

        float l_run = 0.f;
        f32x4 oacc[4];
        const f32x4 zz = {0.f, 0.f, 0.f, 0.f};
        #pragma unroll
        for (int j = 0; j < 4; ++j) oacc[j] = zz;

        for (int kt = 0; kt <= qtb; ++kt) {
            const int tb = kt * 64;
            __syncthreads();   // prior-iteration LDS reads complete
            {   // stage K natural [t][dk]
                const uint16_t* g = &Kbh[(size_t)(tb + sr) * 64 + sc];
                uint4 v0 = *(const uint4*)g, v1 = *(const uint4*)(g + 8);
                *(uint4*)&Ks[sr][sc] = v0;
                *(uint4*)&Ks[sr][sc + 8] = v1;
            }
            {   // stage V^T [dk][t] straight from pre-transposed global
                const uint16_t* g = &Vbh[(size_t)sr * 2048 + tb + sc];
                uint4 v0 = *(const uint4*)g, v1 = *(const uint4*)(g + 8);
                *(uint4*)&Vt[sr][sc] = v0;
                *(uint4*)&Vt[sr][sc + 8] = v1;
            }
            __syncthreads();

            // S^T = K·Q^T
            f32x4 sacc[4];
            #pragma unroll
            for (int i = 0; i < 4; ++i) sacc[i] = zz;
            #pragma unroll
            for (int ks = 0; ks < 2; ++ks) {
                #pragma unroll
                for (int tt = 0; tt < 4; ++tt) {
                    bf16x8 kf = *(const bf16x8*)&Ks[tt * 16 + ll][ks * 32 + quad * 8];
                    sacc[tt] = __builtin_amdgcn_mfma_f32_16x16x32_bf16(kf, qf[ks], sacc[tt], 0, 0, 0);
                }
            }

            // softmax (exp2 domain, no max), P -> Ps
            const bool needMask = (tb + 63 > qw);
            float ls = 0.f;
            #pragma unroll
            for (int tt = 0; tt < 4; ++tt) {
                #pragma unroll
                for (int r = 0; r < 4; ++r) {
                    float v = sacc[tt][r];
                    if (needMask) {
                        int tg = tb + tt * 16 + quad * 4 + r;
                        v = (tg > qg) ? -1e30f : v;
                    }
                    float pe = exp2f(v);
                    sacc[tt][r] = pe;
                    ls += pe;
                }
            }
            ls += __shfl_xor(ls, 16);
            ls += __shfl_xor(ls, 32);
            l_run += ls;
            #pragma unroll
            for (int tt = 0; tt < 4; ++tt) {
                uint2 pv;
                pv.x = pk2bf(sacc[tt][1], sacc[tt][0]);
                pv.y = pk2bf(sacc[tt][3], sacc[tt][2]);
                *(uint2*)&Ps[w * 16 + ll][tt * 16 + quad * 4] = pv;
            }
            __syncthreads();

            // O += P·V
            #pragma unroll
            for (int ks = 0; ks < 2; ++ks) {
                bf16x8 pf = *(const bf16x8*)&Ps[w * 16 + ll][ks * 32 + quad * 8];
                #pragma unroll
                for (int nt = 0; nt < 4; ++nt) {
                    bf16x8 vf = *(const bf16x8*)&Vt[nt * 16 + ll][ks * 32 + quad * 8];
                    oacc[nt] = __builtin_amdgcn_mfma_f32_16x16x32_bf16(pf, vf, oacc[nt], 0, 0, 0);
                }
            }
        }

        if (quad == 0) rbuf[w * 16 + ll] = 1.f / l_run;
        __syncthreads();
        f32x4 li = *(const f32x4*)&rbuf[w * 16 + quad * 4];
        #pragma unroll
        for (int r = 0; r < 4; ++r) {
            int q = q0 + w * 16 + quad * 4 + r;
            #pragma unroll
            for (int nt = 0; nt < 4; ++nt) {
                float v = oacc[nt][r] * li[r];
                Cbh[(size_t)q * 1024 + nt * 16 + ll] = f2bf(v);
            }
        }
        __syncthreads();   // LDS/rbuf safe for next phase
    }
}

// ---------------------------------------------------------------------------
// Output projection: out = CAT(bf16) @ Wo + bo, fp32 out. 128x128 tiles.
// ---------------------------------------------------------------------------
__global__ __launch_bounds__(256) void oproj_mfma_kernel(
    const uint16_t* __restrict__ CATb, const uint16_t* __restrict__ Wot,
    const float* __restrict__ bo, float* __restrict__ out)
{
    __shared__ __align__(16) uint16_t As[128][72];
    __shared__ __align__(16) uint16_t Bs[128][72];
    const int tid = threadIdx.x;
    const int n0 = blockIdx.x * 128;
    const int m0 = blockIdx.y * 128;
    const int lane = tid & 63, w = tid >> 6;
    const int wr = w >> 1, wc = w & 1;
    const int ll = lane & 15, quad = lane >> 4;

    const int ar = tid >> 1, ac = (tid & 1) * 32;

    f32x4 acc[4][4];
    const f32x4 zz = {0.f, 0.f, 0.f, 0.f};
    #pragma unroll
    for (int i = 0; i < 4; ++i)
        #pragma unroll
        for (int j = 0; j < 4; ++j) acc[i][j] = zz;

    for (int k0 = 0; k0 < 1024; k0 += 64) {
        __syncthreads();
        const uint16_t* ag = &CATb[(size_t)(m0 + ar) * 1024 + k0 + ac];
        uint4 a0 = *(const uint4*)(ag);
        uint4 a1 = *(const uint4*)(ag + 8);
        uint4 a2 = *(const uint4*)(ag + 16);
        uint4 a3 = *(const uint4*)(ag + 24);
        const uint16_t* bg = &Wot[(size_t)(n0 + ar) * 1024 + k0 + ac];
        uint4 b0 = *(const uint4*)(bg);
        uint4 b1 = *(const uint4*)(bg + 8);
        uint4 b2 = *(const uint4*)(bg + 16);
        uint4 b3 = *(const uint4*)(bg + 24);
        *(uint4*)&As[ar][ac]      = a0;
        *(uint4*)&As[ar][ac + 8]  = a1;
        *(uint4*)&As[ar][ac + 16] = a2;
        *(uint4*)&As[ar][ac + 24] = a3;
        *(uint4*)&Bs[ar][ac]      = b0;
        *(uint4*)&Bs[ar][ac + 8]  = b1;
        *(uint4*)&Bs[ar][ac + 16] = b2;
        *(uint4*)&Bs[ar][ac + 24] = b3;
        __syncthreads();
        #pragma unroll
        for (int ks = 0; ks < 2; ++ks) {
            bf16x8 af[4], bfv[4];
            #pragma unroll
            for (int mt = 0; mt < 4; ++mt)
                af[mt] = *(const bf16x8*)&As[wr * 64 + mt * 16 + ll][ks * 32 + quad * 8];
            #pragma unroll
            for (int nt = 0; nt < 4; ++nt)
                bfv[nt] = *(const bf16x8*)&Bs[wc * 64 + nt * 16 + ll][ks * 32 + quad * 8];
            #pragma unroll
            for (int mt = 0; mt < 4; ++mt)
                #pragma unroll
                for (int nt = 0; nt < 4; ++nt)
                    acc[mt][nt] = __builtin_amdgcn_mfma_f32_16x16x32_bf16(af[mt], bfv[nt], acc[mt][nt], 0, 0, 0);
        }
    }

    #pragma unroll
    for (int nt = 0; nt < 4; ++nt) {
        const int nl = wc * 64 + nt * 16 + ll;
        const float bval = bo[n0 + nl];
        #pragma unroll
        for (int mt = 0; mt < 4; ++mt) {
            #pragma unroll
            for (int r = 0; r < 4; ++r) {
                int m = m0 + wr * 64 + mt * 16 + quad * 4 + r;
                out[(size_t)m * 1024 + n0 + nl] = acc[mt][nt][r] + bval;
            }
        }
    }
}

extern "C" void kernel_launch(void* const* d_in, const int* in_sizes, int n_in,
                              void* d_out, int out_size, void* d_ws, size_t ws_size,
                              hipStream_t stream) {
    const float* x  = (const float*)d_in[0];
    const float* Wq = (const float*)d_in[1];
    const float* bq = (const float*)d_in[2];
    const float* Wk = (const float*)d_in[3];
    const float* bk = (const float*)d_in[4];
    const float* Wv = (const float*)d_in[5];
    const float* bv = (const float*)d_in[6];
    const float* Wo = (const float*)d_in[7];
    const float* bo = (const float*)d_in[8];

    uint8_t* p = (uint8_t*)d_ws;
    uint16_t* xb   = (uint16_t*)p; p += (size_t)M_ * D_ * 2;            // 16 MiB
    uint16_t* Wt   = (uint16_t*)p; p += (size_t)3 * H_ * DK_ * D_ * 2;  //  6 MiB
    uint16_t* Wot  = (uint16_t*)p; p += (size_t)D_ * D_ * 2;            //  2 MiB
    uint16_t* Qb   = (uint16_t*)p; p += (size_t)B_ * H_ * S_ * DK_ * 2; // 16 MiB
    uint16_t* Kb   = (uint16_t*)p; p += (size_t)B_ * H_ * S_ * DK_ * 2; // 16 MiB
    uint16_t* Vb   = (uint16_t*)p; p += (size_t)B_ * H_ * S_ * DK_ * 2; // 16 MiB (transposed [bh][dk][s])
    uint16_t* CATb = (uint16_t*)p;                                      // 16 MiB

    cvt_bf16_kernel<<<dim3((M_ * D_) / 2048), 256, 0, stream>>>(x, xb, M_ * D_);
    transpose_cvt_kernel<<<dim3(D_ / 64, 1, H_), 256, 0, stream>>>(Wq, Wt, D_, DK_);
    transpose_cvt_kernel<<<dim3(D_ / 64, 1, H_), 256, 0, stream>>>(Wk, Wt + (size_t)H_ * DK_ * D_, D_, DK_);
    transpose_cvt_kernel<<<dim3(D_ / 64, 1, H_), 256, 0, stream>>>(Wv, Wt + (size_t)2 * H_ * DK_ * D_, D_, DK_);
    transpose_cvt_kernel<<<dim3(D_ / 64, D_ / 64, 1), 256, 0, stream>>>(Wo, Wot, D_, D_);

    qkv_mfma_kernel<<<dim3(24, M_ / 128), 256, 0, stream>>>(xb, Wt, bq, bk, bv, Qb, Kb, Vb);
    attn_mfma_kernel<<<dim3(16, B_ * H_), 256, 0, stream>>>(Qb, Kb, Vb, CATb);
    oproj_mfma_kernel<<<dim3(8, M_ / 128), 256, 0, stream>>>(CATb, Wot, bo, (float*)d_out);
}

// Round 5
// 289.882 us; speedup vs baseline: 1.0455x; 1.0455x over previous
//
#include <hip/hip_runtime.h>
#include <stdint.h>

#define B_  4
#define S_  2048
#define D_  1024
#define H_  16
#define DK_ 64
#define M_  (B_ * S_)

typedef __attribute__((ext_vector_type(8))) short bf16x8;
typedef __attribute__((ext_vector_type(4))) float f32x4;

// Q pre-scale: 1/sqrt(64) * log2(e)  (scores land in exp2 domain)
#define QSCALE 0.1803368801111204f

__device__ __forceinline__ uint16_t f2bf(float f) {
    uint32_t u = __builtin_bit_cast(uint32_t, f);
    u = (u + 0x7FFFu + ((u >> 16) & 1u)) >> 16;   // round-to-nearest-even
    return (uint16_t)u;
}

// pack two f32 -> bf16x2 (lo in low half), round-half-up, 3 VALU ops
__device__ __forceinline__ uint32_t pk2bf(float hi, float lo) {
    uint32_t a = __builtin_bit_cast(uint32_t, hi) + 0x8000u;
    uint32_t b = __builtin_bit_cast(uint32_t, lo) + 0x8000u;
    return __builtin_amdgcn_perm(a, b, 0x07060302u);
}

// ---------------------------------------------------------------------------
// fp32 -> bf16 elementwise convert, 8 elems/thread
// ---------------------------------------------------------------------------
__global__ __launch_bounds__(256) void cvt_bf16_kernel(const float* __restrict__ in,
                                                       uint16_t* __restrict__ out, int n) {
    int i = (blockIdx.x * 256 + threadIdx.x) * 8;
    if (i >= n) return;
    float4 a = *(const float4*)&in[i];
    float4 b = *(const float4*)&in[i + 4];
    uint16_t o[8] = {f2bf(a.x), f2bf(a.y), f2bf(a.z), f2bf(a.w),
                     f2bf(b.x), f2bf(b.y), f2bf(b.z), f2bf(b.w)};
    *(uint4*)&out[i] = *(const uint4*)o;
}

// ---------------------------------------------------------------------------
// transpose + convert for the QKV weights, all 48 head-matrices in one launch.
// in: W_sel[h] as [1024][64] fp32 -> Wt[(sel*16+h)*65536 + dk*1024 + d] bf16
// ---------------------------------------------------------------------------
__global__ __launch_bounds__(256) void transpose_cvt_qkv_kernel(
    const float* __restrict__ Wq, const float* __restrict__ Wk,
    const float* __restrict__ Wv, uint16_t* __restrict__ Wt) {
    __shared__ __align__(16) uint16_t tile[64][72];
    const int z = blockIdx.z;          // 0..47
    const int sel = z >> 4, mat = z & 15;
    const float* base = (sel == 0) ? Wq : (sel == 1) ? Wk : Wv;
    const float* inm = base + (size_t)mat * 1024 * 64;
    uint16_t* outm = Wt + (size_t)z * 65536;
    const int r0 = blockIdx.x * 64;    // d
    const int t = threadIdx.x;
    const int lr = t >> 2, lc = (t & 3) * 16;
    uint16_t tmp[16];
    #pragma unroll
    for (int j = 0; j < 16; j += 4) {
        float4 v = *(const float4*)&inm[(size_t)(r0 + lr) * 64 + lc + j];
        tmp[j] = f2bf(v.x); tmp[j + 1] = f2bf(v.y); tmp[j + 2] = f2bf(v.z); tmp[j + 3] = f2bf(v.w);
    }
    *(uint4*)&tile[lr][lc]     = ((const uint4*)tmp)[0];
    *(uint4*)&tile[lr][lc + 8] = ((const uint4*)tmp)[1];
    __syncthreads();
    const int oc = t >> 2, orr = (t & 3) * 16;
    uint16_t ot[16];
    #pragma unroll
    for (int j = 0; j < 16; ++j) ot[j] = tile[orr + j][oc];
    *(uint4*)&outm[(size_t)oc * 1024 + r0 + orr]     = ((const uint4*)ot)[0];
    *(uint4*)&outm[(size_t)oc * 1024 + r0 + orr + 8] = ((const uint4*)ot)[1];
}

// ---------------------------------------------------------------------------
// transpose + convert: in [R][C] fp32 -> out [C][R] bf16 (for Wo)
// ---------------------------------------------------------------------------
__global__ __launch_bounds__(256) void transpose_cvt_kernel(
    const float* __restrict__ in, uint16_t* __restrict__ out, int R, int C) {
    __shared__ __align__(16) uint16_t tile[64][72];
    const float* inm = in;
    uint16_t* outm = out;
    const int r0 = blockIdx.x * 64, c0 = blockIdx.y * 64;
    const int t = threadIdx.x;
    const int lr = t >> 2, lc = (t & 3) * 16;
    uint16_t tmp[16];
    #pragma unroll
    for (int j = 0; j < 16; j += 4) {
        float4 v = *(const float4*)&inm[(size_t)(r0 + lr) * C + c0 + lc + j];
        tmp[j] = f2bf(v.x); tmp[j + 1] = f2bf(v.y); tmp[j + 2] = f2bf(v.z); tmp[j + 3] = f2bf(v.w);
    }
    *(uint4*)&tile[lr][lc]     = ((const uint4*)tmp)[0];
    *(uint4*)&tile[lr][lc + 8] = ((const uint4*)tmp)[1];
    __syncthreads();
    const int oc = t >> 2, orr = (t & 3) * 16;
    uint16_t ot[16];
    #pragma unroll
    for (int j = 0; j < 16; ++j) ot[j] = tile[orr + j][oc];
    *(uint4*)&outm[(size_t)(c0 + oc) * R + r0 + orr]     = ((const uint4*)ot)[0];
    *(uint4*)&outm[(size_t)(c0 + oc) * R + r0 + orr + 8] = ((const uint4*)ot)[1];
}

// ---------------------------------------------------------------------------
// QKV projection, MFMA. C[128 x 128] per block; 4 waves in 2x2, 64x64/wave.
// Q pre-scaled by QSCALE. V written TRANSPOSED [bh][dk][s].
// ---------------------------------------------------------------------------
__global__ __launch_bounds__(256) void qkv_mfma_kernel(
    const uint16_t* __restrict__ xb, const uint16_t* __restrict__ Wt,
    const float* __restrict__ bq, const float* __restrict__ bk, const float* __restrict__ bv,
    uint16_t* __restrict__ Q, uint16_t* __restrict__ K, uint16_t* __restrict__ V)
{
    __shared__ __align__(16) uint16_t As[128][72];
    __shared__ __align__(16) uint16_t Bs[128][72];
    const int tid = threadIdx.x;
    const int nb = blockIdx.x;                  // 0..23
    const int sel = nb >> 3, npair = nb & 7;
    const int m0 = blockIdx.y * 128;
    const int lane = tid & 63, w = tid >> 6;
    const int wr = w >> 1, wc = w & 1;
    const int ll = lane & 15, quad = lane >> 4;

    const uint16_t* Bg = Wt + (size_t)nb * 128 * 1024;
    const float* bias = (sel == 0) ? bq : (sel == 1) ? bk : bv;

    const int ar = tid >> 1, ac = (tid & 1) * 32;

    f32x4 acc[4][4];
    const f32x4 zz = {0.f, 0.f, 0.f, 0.f};
    #pragma unroll
    for (int i = 0; i < 4; ++i)
        #pragma unroll
        for (int j = 0; j < 4; ++j) acc[i][j] = zz;

    for (int k0 = 0; k0 < 1024; k0 += 64) {
        __syncthreads();
        const uint16_t* ag = &xb[(size_t)(m0 + ar) * 1024 + k0 + ac];
        uint4 a0 = *(const uint4*)(ag);
        uint4 a1 = *(const uint4*)(ag + 8);
        uint4 a2 = *(const uint4*)(ag + 16);
        uint4 a3 = *(const uint4*)(ag + 24);
        const uint16_t* bg = &Bg[(size_t)ar * 1024 + k0 + ac];
        uint4 b0 = *(const uint4*)(bg);
        uint4 b1 = *(const uint4*)(bg + 8);
        uint4 b2 = *(const uint4*)(bg + 16);
        uint4 b3 = *(const uint4*)(bg + 24);
        *(uint4*)&As[ar][ac]      = a0;
        *(uint4*)&As[ar][ac + 8]  = a1;
        *(uint4*)&As[ar][ac + 16] = a2;
        *(uint4*)&As[ar][ac + 24] = a3;
        *(uint4*)&Bs[ar][ac]      = b0;
        *(uint4*)&Bs[ar][ac + 8]  = b1;
        *(uint4*)&Bs[ar][ac + 16] = b2;
        *(uint4*)&Bs[ar][ac + 24] = b3;
        __syncthreads();
        #pragma unroll
        for (int ks = 0; ks < 2; ++ks) {
            bf16x8 af[4], bfv[4];
            #pragma unroll
            for (int mt = 0; mt < 4; ++mt)
                af[mt] = *(const bf16x8*)&As[wr * 64 + mt * 16 + ll][ks * 32 + quad * 8];
            #pragma unroll
            for (int nt = 0; nt < 4; ++nt)
                bfv[nt] = *(const bf16x8*)&Bs[wc * 64 + nt * 16 + ll][ks * 32 + quad * 8];
            #pragma unroll
            for (int mt = 0; mt < 4; ++mt)
                #pragma unroll
                for (int nt = 0; nt < 4; ++nt)
                    acc[mt][nt] = __builtin_amdgcn_mfma_f32_16x16x32_bf16(af[mt], bfv[nt], acc[mt][nt], 0, 0, 0);
        }
    }

    if (sel == 2) {
        #pragma unroll
        for (int nt = 0; nt < 4; ++nt) {
            const int nl = wc * 64 + nt * 16 + ll;
            const int hh = npair * 2 + (nl >> 6);
            const int dk = nl & 63;
            const float bval = bias[npair * 128 + nl];
            #pragma unroll
            for (int mt = 0; mt < 4; ++mt) {
                int m = m0 + wr * 64 + mt * 16 + quad * 4;
                int b = m >> 11, s = m & 2047;
                uint2 pv;
                pv.x = pk2bf(acc[mt][nt][1] + bval, acc[mt][nt][0] + bval);
                pv.y = pk2bf(acc[mt][nt][3] + bval, acc[mt][nt][2] + bval);
                *(uint2*)&V[((size_t)(b * 16 + hh) * 64 + dk) * 2048 + s] = pv;
            }
        }
    } else {
        uint16_t* Out = (sel == 0) ? Q : K;
        const float qs = (sel == 0) ? QSCALE : 1.0f;
        #pragma unroll
        for (int nt = 0; nt < 4; ++nt) {
            const int nl = wc * 64 + nt * 16 + ll;
            const int hh = npair * 2 + (nl >> 6);
            const int dk = nl & 63;
            const float bval = bias[npair * 128 + nl];
            #pragma unroll
            for (int mt = 0; mt < 4; ++mt) {
                #pragma unroll
                for (int r = 0; r < 4; ++r) {
                    int m = m0 + wr * 64 + mt * 16 + quad * 4 + r;
                    int b = m >> 11, s = m & 2047;
                    float v = (acc[mt][nt][r] + bval) * qs;
                    Out[((size_t)(b * 16 + hh) * 2048 + s) * 64 + dk] = f2bf(v);
                }
            }
        }
    }
}

// ---------------------------------------------------------------------------
// Flash attention, MFMA, S^T = K·Q^T. 128-row q-blocks; block pairs tiles
// (15-p, p) for uniform 36 kt-tiles/block. 4 waves x 32 q-rows, Q direct
// from global. Ps is wave-private (no barrier between P write and read).
// Row-sum l via ones-column MFMA. exp2-domain softmax, no running max.
// ---------------------------------------------------------------------------
__global__ __launch_bounds__(256) void attn_mfma_kernel(
    const uint16_t* __restrict__ Q, const uint16_t* __restrict__ K,
    const uint16_t* __restrict__ Vg, uint16_t* __restrict__ CAT)
{
    __shared__ __align__(16) uint16_t Ks[64][72];
    __shared__ __align__(16) uint16_t Vt[64][72];
    __shared__ __align__(16) uint16_t Ps[128][72];

    const int tid = threadIdx.x;
    const int lane = tid & 63, w = tid >> 6;
    const int ll = lane & 15, quad = lane >> 4;
    const int p = blockIdx.x;          // 0..7
    const int bh = blockIdx.y;
    const int b = bh >> 4, h = bh & 15;

    const uint16_t* Qbh = Q + (size_t)bh * S_ * 64;
    const uint16_t* Kbh = K + (size_t)bh * S_ * 64;
    const uint16_t* Vbh = Vg + (size_t)bh * 64 * S_;   // [dk][s]
    uint16_t* Cbh = CAT + (size_t)b * 2048 * 1024 + h * 64;

    const int sr = tid >> 2, sc = (tid & 3) * 16;      // staging coords

    // ones B-fragment: B[k][0] = 1 -> row sums land in output col 0
    bf16x8 onesf;
    #pragma unroll
    for (int j = 0; j < 8; ++j) onesf[j] = (ll == 0) ? (short)0x3F80 : (short)0;

    const f32x4 zz = {0.f, 0.f, 0.f, 0.f};

    #pragma unroll 1
    for (int phase = 0; phase < 2; ++phase) {
        const int qtb = (phase == 0) ? (15 - p) : p;
        const int q0 = qtb * 128;
        const int qw = q0 + w * 32;     // this wave's q rows [qw, qw+32)

        bf16x8 qf[2][2];
        #pragma unroll
        for (int mt = 0; mt < 2; ++mt)
            #pragma unroll
            for (int ks = 0; ks < 2; ++ks)
                qf[mt][ks] = *(const bf16x8*)&Qbh[(size_t)(qw + mt * 16 + ll) * 64 + ks * 32 + quad * 8];

        f32x4 oacc[2][4];
        f32x4 lacc[2];
        #pragma unroll
        for (int i = 0; i < 2; ++i) {
            lacc[i] = zz;
            #pragma unroll
            for (int j = 0; j < 4; ++j) oacc[i][j] = zz;
        }

        const int ktmax = 2 * qtb + 1;

        for (int kt = 0; kt <= ktmax; ++kt) {
            const int tb = kt * 64;
            __syncthreads();   // all waves done reading Ks/Vt of prior tile
            {   // stage K natural [t][dk]
                const uint16_t* g = &Kbh[(size_t)(tb + sr) * 64 + sc];
                uint4 v0 = *(const uint4*)g, v1 = *(const uint4*)(g + 8);
                *(uint4*)&Ks[sr][sc] = v0;
                *(uint4*)&Ks[sr][sc + 8] = v1;
            }
            {   // stage V^T [dk][t] from pre-transposed global
                const uint16_t* g = &Vbh[(size_t)sr * 2048 + tb + sc];
                uint4 v0 = *(const uint4*)g, v1 = *(const uint4*)(g + 8);
                *(uint4*)&Vt[sr][sc] = v0;
                *(uint4*)&Vt[sr][sc + 8] = v1;
            }
            __syncthreads();

            const bool active = (tb <= qw + 31);
            if (active) {
                // S^T = K·Q^T  (M = t rows of K, N = q)
                f32x4 sacc[4][2];
                #pragma unroll
                for (int i = 0; i < 4; ++i)
                    #pragma unroll
                    for (int j = 0; j < 2; ++j) sacc[i][j] = zz;
                #pragma unroll
                for (int ks = 0; ks < 2; ++ks) {
                    #pragma unroll
                    for (int tt = 0; tt < 4; ++tt) {
                        bf16x8 kf = *(const bf16x8*)&Ks[tt * 16 + ll][ks * 32 + quad * 8];
                        #pragma unroll
                        for (int mt = 0; mt < 2; ++mt)
                            sacc[tt][mt] = __builtin_amdgcn_mfma_f32_16x16x32_bf16(kf, qf[mt][ks], sacc[tt][mt], 0, 0, 0);
                    }
                }

                // mask + exp2 + pack P into wave-private Ps rows
                const bool needMask = (tb + 63 > qw);
                #pragma unroll
                for (int mt = 0; mt < 2; ++mt) {
                    const int qg = qw + mt * 16 + ll;
                    #pragma unroll
                    for (int tt = 0; tt < 4; ++tt) {
                        #pragma unroll
                        for (int r = 0; r < 4; ++r) {
                            float v = sacc[tt][mt][r];
                            if (needMask) {
                                int tg = tb + tt * 16 + quad * 4 + r;
                                v = (tg > qg) ? -1e30f : v;
                            }
                            sacc[tt][mt][r] = __builtin_amdgcn_exp2f(v);
                        }
                        uint2 pv;
                        pv.x = pk2bf(sacc[tt][mt][1], sacc[tt][mt][0]);
                        pv.y = pk2bf(sacc[tt][mt][3], sacc[tt][mt][2]);
                        *(uint2*)&Ps[w * 32 + mt * 16 + ll][tt * 16 + quad * 4] = pv;
                    }
                }

                // O += P·V ; l += P·ones   (Ps rows are this wave's own:
                // per-wave DS ordering makes the write->read safe w/o barrier)
                #pragma unroll
                for (int ks = 0; ks < 2; ++ks) {
                    bf16x8 pf[2], vf[4];
                    #pragma unroll
                    for (int mt = 0; mt < 2; ++mt)
                        pf[mt] = *(const bf16x8*)&Ps[w * 32 + mt * 16 + ll][ks * 32 + quad * 8];
                    #pragma unroll
                    for (int nt = 0; nt < 4; ++nt)
                        vf[nt] = *(const bf16x8*)&Vt[nt * 16 + ll][ks * 32 + quad * 8];
                    #pragma unroll
                    for (int mt = 0; mt < 2; ++mt) {
                        lacc[mt] = __builtin_amdgcn_mfma_f32_16x16x32_bf16(pf[mt], onesf, lacc[mt], 0, 0, 0);
                        #pragma unroll
                        for (int nt = 0; nt < 4; ++nt)
                            oacc[mt][nt] = __builtin_amdgcn_mfma_f32_16x16x32_bf16(pf[mt], vf[nt], oacc[mt][nt], 0, 0, 0);
                    }
                }
            }
        }

        // epilogue: l lives in lanes ll==0 (output col 0); broadcast within
        // each quad group via shfl, then scale + store
        #pragma unroll
        for (int mt = 0; mt < 2; ++mt) {
            f32x4 li;
            #pragma unroll
            for (int r = 0; r < 4; ++r)
                li[r] = 1.0f / __shfl(lacc[mt][r], lane & 48);
            #pragma unroll
            for (int r = 0; r < 4; ++r) {
                int q = qw + mt * 16 + quad * 4 + r;
                #pragma unroll
                for (int nt = 0; nt < 4; ++nt) {
                    float v = oacc[mt][nt][r] * li[r];
                    Cbh[(size_t)q * 1024 + nt * 16 + ll] = f2bf(v);
                }
            }
        }
        // next phase's first __syncthreads (top of kt loop) guards restaging
    }
}

// ---------------------------------------------------------------------------
// Output projection: out = CAT(bf16) @ Wo + bo, fp32 out. 128x128 tiles.
// ---------------------------------------------------------------------------
__global__ __launch_bounds__(256) void oproj_mfma_kernel(
    const uint16_t* __restrict__ CATb, const uint16_t* __restrict__ Wot,
    const float* __restrict__ bo, float* __restrict__ out)
{
    __shared__ __align__(16) uint16_t As[128][72];
    __shared__ __align__(16) uint16_t Bs[128][72];
    const int tid = threadIdx.x;
    const int n0 = blockIdx.x * 128;
    const int m0 = blockIdx.y * 128;
    const int lane = tid & 63, w = tid >> 6;
    const int wr = w >> 1, wc = w & 1;
    const int ll = lane & 15, quad = lane >> 4;

    const int ar = tid >> 1, ac = (tid & 1) * 32;

    f32x4 acc[4][4];
    const f32x4 zz = {0.f, 0.f, 0.f, 0.f};
    #pragma unroll
    for (int i = 0; i < 4; ++i)
        #pragma unroll
        for (int j = 0; j < 4; ++j) acc[i][j] = zz;

    for (int k0 = 0; k0 < 1024; k0 += 64) {
        __syncthreads();
        const uint16_t* ag = &CATb[(size_t)(m0 + ar) * 1024 + k0 + ac];
        uint4 a0 = *(const uint4*)(ag);
        uint4 a1 = *(const uint4*)(ag + 8);
        uint4 a2 = *(const uint4*)(ag + 16);
        uint4 a3 = *(const uint4*)(ag + 24);
        const uint16_t* bg = &Wot[(size_t)(n0 + ar) * 1024 + k0 + ac];
        uint4 b0 = *(const uint4*)(bg);
        uint4 b1 = *(const uint4*)(bg + 8);
        uint4 b2 = *(const uint4*)(bg + 16);
        uint4 b3 = *(const uint4*)(bg + 24);
        *(uint4*)&As[ar][ac]      = a0;
        *(uint4*)&As[ar][ac + 8]  = a1;
        *(uint4*)&As[ar][ac + 16] = a2;
        *(uint4*)&As[ar][ac + 24] = a3;
        *(uint4*)&Bs[ar][ac]      = b0;
        *(uint4*)&Bs[ar][ac + 8]  = b1;
        *(uint4*)&Bs[ar][ac + 16] = b2;
        *(uint4*)&Bs[ar][ac + 24] = b3;
        __syncthreads();
        #pragma unroll
        for (int ks = 0; ks < 2; ++ks) {
            bf16x8 af[4], bfv[4];
            #pragma unroll
            for (int mt = 0; mt < 4; ++mt)
                af[mt] = *(const bf16x8*)&As[wr * 64 + mt * 16 + ll][ks * 32 + quad * 8];
            #pragma unroll
            for (int nt = 0; nt < 4; ++nt)
                bfv[nt] = *(const bf16x8*)&Bs[wc * 64 + nt * 16 + ll][ks * 32 + quad * 8];
            #pragma unroll
            for (int mt = 0; mt < 4; ++mt)
                #pragma unroll
                for (int nt = 0; nt < 4; ++nt)
                    acc[mt][nt] = __builtin_amdgcn_mfma_f32_16x16x32_bf16(af[mt], bfv[nt], acc[mt][nt], 0, 0, 0);
        }
    }

    #pragma unroll
    for (int nt = 0; nt < 4; ++nt) {
        const int nl = wc * 64 + nt * 16 + ll;
        const float bval = bo[n0 + nl];
        #pragma unroll
        for (int mt = 0; mt < 4; ++mt) {
            #pragma unroll
            for (int r = 0; r < 4; ++r) {
                int m = m0 + wr * 64 + mt * 16 + quad * 4 + r;
                out[(size_t)m * 1024 + n0 + nl] = acc[mt][nt][r] + bval;
            }
        }
    }
}

extern "C" void kernel_launch(void* const* d_in, const int* in_sizes, int n_in,
                              void* d_out, int out_size, void* d_ws, size_t ws_size,
                              hipStream_t stream) {
    const float* x  = (const float*)d_in[0];
    const float* Wq = (const float*)d_in[1];
    const float* bq = (const float*)d_in[2];
    const float* Wk = (const float*)d_in[3];
    const float* bk = (const float*)d_in[4];
    const float* Wv = (const float*)d_in[5];
    const float* bv = (const float*)d_in[6];
    const float* Wo = (const float*)d_in[7];
    const float* bo = (const float*)d_in[8];

    uint8_t* p = (uint8_t*)d_ws;
    uint16_t* xb   = (uint16_t*)p; p += (size_t)M_ * D_ * 2;            // 16 MiB
    uint16_t* Wt   = (uint16_t*)p; p += (size_t)3 * H_ * DK_ * D_ * 2;  //  6 MiB
    uint16_t* Wot  = (uint16_t*)p; p += (size_t)D_ * D_ * 2;            //  2 MiB
    uint16_t* Qb   = (uint16_t*)p; p += (size_t)B_ * H_ * S_ * DK_ * 2; // 16 MiB
    uint16_t* Kb   = (uint16_t*)p; p += (size_t)B_ * H_ * S_ * DK_ * 2; // 16 MiB
    uint16_t* Vb   = (uint16_t*)p; p += (size_t)B_ * H_ * S_ * DK_ * 2; // 16 MiB (transposed [bh][dk][s])
    uint16_t* CATb = (uint16_t*)p;                                      // 16 MiB

    cvt_bf16_kernel<<<dim3((M_ * D_) / 2048), 256, 0, stream>>>(x, xb, M_ * D_);
    transpose_cvt_qkv_kernel<<<dim3(16, 1, 48), 256, 0, stream>>>(Wq, Wk, Wv, Wt);
    transpose_cvt_kernel<<<dim3(D_ / 64, D_ / 64, 1), 256, 0, stream>>>(Wo, Wot, D_, D_);

    qkv_mfma_kernel<<<dim3(24, M_ / 128), 256, 0, stream>>>(xb, Wt, bq, bk, bv, Qb, Kb, Vb);
    attn_mfma_kernel<<<dim3(8, B_ * H_), 256, 0, stream>>>(Qb, Kb, Vb, CATb);
    oproj_mfma_kernel<<<dim3(8, M_ / 128), 256, 0, stream>>>(CATb, Wot, bo, (float*)d_out);
}